// Round 4
// baseline (285.116 us; speedup 1.0000x reference)
//
#include <hip/hip_runtime.h>

#define H 512
#define WID 1024
#define HW (H*WID)
#define B 4
#define K 8
#define NB 1024

// ws layout in 4-byte words
#define OFF_LOSS  0
#define OFF_STATS 16                      // B*K*5 = 160 floats: cnt,sx,sy,ss,ss2
#define OFF_FIN   176                     // B*K*4 floats: cx,cy,-sexp,cnt
#define OFF_PART  512                     // B*G*K*NB packed u32 (pos<<16|cnt)

static __device__ __forceinline__ float frcp(float x){
#if __has_builtin(__builtin_amdgcn_rcpf)
  return __builtin_amdgcn_rcpf(x);
#else
  return 1.0f / x;
#endif
}
static __device__ __forceinline__ float ftanh(float x){
  return 1.0f - 2.0f * frcp(__expf(2.0f*x) + 1.0f);
}
static __device__ __forceinline__ float fsigmoid(float x){
  return frcp(1.0f + __expf(-x));
}

// ---------------- Kernel 1: per-(b,k) mask statistics (wave-per-k) ----------------
// 512 thr = 8 waves; wave w owns k=w+1. Branchless int4/float4. 256 blocks/b
// -> 1024 blocks, 4 blocks/CU (VGPR 12) -> 32 waves/CU.
__global__ __launch_bounds__(512) void k1_stats(const float* __restrict__ pred,
                                                const int* __restrict__ inst,
                                                float* __restrict__ ws) {
  const int b = blockIdx.y;
  const int wv   = threadIdx.x >> 6;
  const int lane = threadIdx.x & 63;
  const int kk   = wv + 1;
  const float4* sig4 = (const float4*)(pred + (size_t)(8*b + 5) * HW);
  const int4*   ins4 = (const int4*)(inst + (size_t)(2*b + 1) * HW);
  const int CH4   = HW / (256*4);         // 512 groups/block
  const int base4 = blockIdx.x * CH4;
  float cnt=0.f, sx=0.f, sy=0.f, ss=0.f, ss2=0.f;
  for (int q = lane; q < CH4; q += 64) {
    const int4   iv = ins4[base4 + q];
    const float4 sv = sig4[base4 + q];
    const int p = (base4 + q) * 4;
    const float xm0 = (float)(p & (WID-1)) * (2.0f/2047.0f);
    const float ym  = (float)(p >> 10)     * (1.0f/1023.0f);
    const float m0 = (iv.x==kk)?1.f:0.f, m1=(iv.y==kk)?1.f:0.f,
                m2 = (iv.z==kk)?1.f:0.f, m3=(iv.w==kk)?1.f:0.f;
    cnt += (m0+m1)+(m2+m3);
    sx  += m0*xm0 + m1*(xm0+1.0f*(2.0f/2047.0f)) + m2*(xm0+2.0f*(2.0f/2047.0f)) + m3*(xm0+3.0f*(2.0f/2047.0f));
    sy  += ((m0+m1)+(m2+m3))*ym;
    ss  += m0*sv.x + m1*sv.y + m2*sv.z + m3*sv.w;
    ss2 += m0*sv.x*sv.x + m1*sv.y*sv.y + m2*sv.z*sv.z + m3*sv.w*sv.w;
  }
  #pragma unroll
  for (int o=1;o<64;o<<=1){
    cnt+=__shfl_xor(cnt,o,64);
    sx +=__shfl_xor(sx, o,64);
    sy +=__shfl_xor(sy, o,64);
    ss +=__shfl_xor(ss, o,64);
    ss2+=__shfl_xor(ss2,o,64);
  }
  if (lane == 0) {
    float* st = ws + OFF_STATS + (b*K + wv)*5;
    atomicAdd(st+0, cnt);
    atomicAdd(st+1, sx);
    atomicAdd(st+2, sy);
    atomicAdd(st+3, ss);
    atomicAdd(st+4, ss2);
  }
}

// ---------------- Kernel 2: finalize stats + var loss ----------------
__global__ void k2_fin(float* __restrict__ ws) {
  const int t = threadIdx.x;
  if (t >= B*K) return;
  const float* st = ws + OFF_STATS + t*5;
  const float cnt = st[0], sx = st[1], sy = st[2], ss = st[3], ss2 = st[4];
  const float present = (cnt > 0.0f) ? 1.0f : 0.0f;
  const float safe = fmaxf(cnt, 1.0f);
  const float cx = sx/safe, cy = sy/safe, sm = ss/safe;
  const float var = (ss2 - 2.0f*sm*ss + sm*sm*cnt)/safe;   // N_SIGMA=1
  const float sexp = expf(10.0f * sm);
  float* fin = ws + OFF_FIN + t*4;
  fin[0]=cx; fin[1]=cy; fin[2]=-sexp; fin[3]=cnt;
  atomicAdd(ws + OFF_LOSS, present * 10.0f * var * (1.0f/3.0f));  // W_VAR=10, /(B-1)
}

// ---------------- Kernel 3: main pass — LDS histograms, plain-store flush ----------------
// Grid (G, B), 256 thr, 33 KB LDS -> 4 blocks/CU, 16 waves/CU. Flush is plain
// coalesced u32 stores of the packed per-block histogram (NO global atomics).
__global__ __launch_bounds__(256) void k3_main(const float* __restrict__ pred,
                                               const int* __restrict__ inst,
                                               float* __restrict__ ws,
                                               unsigned int* __restrict__ part,
                                               int G) {
  const int b = blockIdx.y, g = blockIdx.x;
  __shared__ unsigned int hist[K*NB];           // pos<<16 | cnt, 32 KiB
  __shared__ float4 finL[K];                    // {cx, cy, -sexp, cnt}
  for (int i = threadIdx.x; i < K*NB; i += 256) hist[i] = 0;
  if (threadIdx.x < K) {
    const float* fin = ws + OFF_FIN + (b*K + threadIdx.x)*4;
    finL[threadIdx.x] = make_float4(fin[0], fin[1], fin[2], fin[3]);
  }
  __syncthreads();
  const float4* p0 = (const float4*)(pred + (size_t)(8*b+1)*HW);
  const float4* p1 = (const float4*)(pred + (size_t)(8*b+3)*HW);
  const float4* p3 = (const float4*)(pred + (size_t)(8*b+7)*HW);
  const int4*   in4 = (const int4*)(inst + (size_t)(2*b+1)*HW);
  const int lane = threadIdx.x & 63;
  float sAcc = 0.0f;
  const int CH4   = HW / (G*4);
  const int base4 = g * CH4;
  for (int q = threadIdx.x; q < CH4; q += 256) {
    const int idx = base4 + q;
    const int4   iv = in4[idx];
    const float4 f0 = p0[idx];
    const float4 f1 = p1[idx];
    const float4 f3 = p3[idx];
    const int p = idx * 4;
    const float xm0 = (float)(p & (WID-1)) * (2.0f/2047.0f);
    const float ym  = (float)(p >> 10)     * (1.0f/1023.0f);
    const int   ivv[4] = {iv.x, iv.y, iv.z, iv.w};
    const float a0v[4] = {f0.x, f0.y, f0.z, f0.w};
    const float a1v[4] = {f1.x, f1.y, f1.z, f1.w};
    const float a3v[4] = {f3.x, f3.y, f3.z, f3.w};
    #pragma unroll
    for (int e4 = 0; e4 < 4; e4++) {
      const int ivp = ivv[e4];
      const float sex = ftanh(a0v[e4]) + xm0 + (float)e4*(2.0f/2047.0f);
      const float sey = ftanh(a1v[e4]) + ym;
      const float sd  = fsigmoid(a3v[e4]);
      if (ivp == 0) sAcc += sd*sd;
      #pragma unroll
      for (int j=0;j<K;j++){
        const int k = (j + lane) & (K-1);   // rotation: 8 histograms active/wave
        const float4 f = finL[k];
        const float dx = sex - f.x;
        const float dy = sey - f.y;
        const float dist = __expf(f.z*(dx*dx + dy*dy));  // (0,1]
        const bool own = (ivp == k+1);
        float e;
        if (own) { const float d = sd - dist; sAcc += d*d; e = 2.0f - 2.0f*dist; }
        else     { e = 2.0f*dist; }
        int bu = (int)(e * (NB*0.5f));
        if (bu > NB-1) bu = NB-1;
        atomicAdd(&hist[k*NB + bu], own ? 0x10001u : 1u);
      }
    }
  }
  __syncthreads();
  // plain coalesced flush of packed histogram (px/block <= 32768 < 65536 -> no overflow)
  unsigned int* dst = part + ((size_t)b*G + g)*(K*NB);
  for (int i = threadIdx.x; i < K*NB; i += 256) dst[i] = hist[i];
  #pragma unroll
  for (int o=1;o<64;o<<=1) sAcc += __shfl_xor(sAcc, o, 64);
  __shared__ float wsum[4];
  if ((threadIdx.x & 63) == 0) wsum[threadIdx.x>>6] = sAcc;
  __syncthreads();
  if (threadIdx.x == 0) {
    const float tot = wsum[0]+wsum[1]+wsum[2]+wsum[3];
    atomicAdd(ws + OFF_LOSS, tot * (1.0f/((float)HW * 3.0f)));  // W_SEED, /npix, /(B-1)
  }
}

// ---------------- Kernel 4: G-way reduce + Lovász (parallel block scan) ----------------
__global__ __launch_bounds__(256) void k4_lovasz(const unsigned int* __restrict__ part,
                                                 float* __restrict__ ws, int G) {
  const int bk = blockIdx.x;                    // b*K + k
  const int b = bk >> 3, k = bk & 7;
  const float cntF = ws[OFF_FIN + bk*4 + 3];
  if (cntF <= 0.0f) return;
  const double Pd = (double)cntF;
  const int t = threadIdx.x;
  const int lane = t & 63, wv = t >> 6;
  // thread t owns descending-order positions t*4 .. t*4+3 -> buckets NB-1-(t*4+j)
  unsigned int cnt[4] = {0,0,0,0}, pos[4] = {0,0,0,0};
  const unsigned int* base = part + (size_t)b*G*K*NB + (size_t)k*NB;
  for (int g = 0; g < G; g++) {
    const unsigned int* pg = base + (size_t)g*(K*NB);
    #pragma unroll
    for (int j = 0; j < 4; j++) {
      const unsigned int v = pg[NB-1 - (t*4 + j)];
      cnt[j] += v & 0xFFFFu;
      pos[j] += v >> 16;
    }
  }
  const int lc = (int)(cnt[0]+cnt[1]+cnt[2]+cnt[3]);
  const int lp = (int)(pos[0]+pos[1]+pos[2]+pos[3]);
  // block-wide exclusive prefix over thread order (== descending error order)
  int ic = lc, ip = lp;
  #pragma unroll
  for (int o=1;o<64;o<<=1){
    const int vc = __shfl_up(ic, o, 64);
    const int vp = __shfl_up(ip, o, 64);
    if (lane >= o) { ic += vc; ip += vp; }
  }
  __shared__ int wtc[4], wtp[4];
  if (lane == 63) { wtc[wv] = ic; wtp[wv] = ip; }
  __syncthreads();
  int offc = 0, offp = 0;
  for (int w = 0; w < wv; w++) { offc += wtc[w]; offp += wtp[w]; }
  int irun = offc + ic - lc;                    // exclusive cnt prefix
  int crun = offp + ip - lp;                    // exclusive pos prefix
  double acc = 0.0;
  #pragma unroll
  for (int j = 0; j < 4; j++) {
    const int n = (int)cnt[j];
    if (n) {
      const int bu = NB-1 - (t*4 + j);
      const double jac0 = (irun==0) ? 0.0 : 1.0 - (Pd - crun)/(Pd + irun - crun);
      irun += n; crun += (int)pos[j];
      const double jac1 = 1.0 - (Pd - crun)/(Pd + irun - crun);
      acc += ((bu + 0.5) * (2.0/NB)) * (jac1 - jac0);
    } else {
      irun += n;                                 // n==0: nothing
    }
  }
  #pragma unroll
  for (int o=1;o<64;o<<=1) acc += __shfl_xor(acc, o, 64);
  __shared__ double racc[4];
  if (lane == 0) racc[wv] = acc;
  __syncthreads();
  if (t == 0) {
    const double tot = racc[0]+racc[1]+racc[2]+racc[3];
    atomicAdd(ws + OFF_LOSS, (float)(tot * (1.0/3.0)));   // W_INST=1, /(B-1)
  }
}

// ---------------- Kernel 5: write output ----------------
__global__ void k5_out(const float* __restrict__ ws, float* __restrict__ out) {
  if (threadIdx.x == 0) out[0] = ws[OFF_LOSS];
}

extern "C" void kernel_launch(void* const* d_in, const int* in_sizes, int n_in,
                              void* d_out, int out_size, void* d_ws, size_t ws_size,
                              hipStream_t stream) {
  const float* pred = (const float*)d_in[0];
  const int*   inst = (const int*)d_in[1];
  float* ws  = (float*)d_ws;
  float* out = (float*)d_out;
  unsigned int* part = ((unsigned int*)d_ws) + OFF_PART;
  // pick G (blocks per image in k3) by ws capacity; all divide HW, px/block<=32768
  int G = 128;
  if (ws_size < (size_t)(OFF_PART + (size_t)B*128*K*NB) * 4) G = 32;
  if (ws_size < (size_t)(OFF_PART + (size_t)B*32 *K*NB) * 4) G = 16;
  hipMemsetAsync(d_ws, 0, (size_t)OFF_PART*4, stream);   // zero LOSS/STATS/FIN only
  k1_stats<<<dim3(256,B), 512, 0, stream>>>(pred, inst, ws);
  k2_fin  <<<1, 64, 0, stream>>>(ws);
  k3_main <<<dim3(G,B), 256, 0, stream>>>(pred, inst, ws, part, G);
  k4_lovasz<<<B*K, 256, 0, stream>>>(part, ws, G);
  k5_out  <<<1, 64, 0, stream>>>(ws, out);
}

// Round 5
// 224.806 us; speedup vs baseline: 1.2683x; 1.2683x over previous
//
#include <hip/hip_runtime.h>

#define H 512
#define WID 1024
#define HW (H*WID)
#define B 4
#define K 8
#define NB 1024

// ws word (4-byte) layout
#define OFF_LOSS  0
#define OFF_STATS 16                       // B*K*5 floats: cnt,sx,sy,ss,ss2
#define OFF_FIN   176                      // B*K*4 floats: cx,cy,-sexp,cnt
#define OFF_RED   512                      // 2*B*K*NB u32: cnt[], then pos[]
#define OFF_PART  (OFF_RED + 2*B*K*NB)     // B*G*K*NB packed u32 (pos<<16|cnt)

static __device__ __forceinline__ float frcp(float x){
#if __has_builtin(__builtin_amdgcn_rcpf)
  return __builtin_amdgcn_rcpf(x);
#else
  return 1.0f / x;
#endif
}
static __device__ __forceinline__ float ftanh(float x){
  return 1.0f - 2.0f * frcp(__expf(2.0f*x) + 1.0f);
}
static __device__ __forceinline__ float fsigmoid(float x){
  return frcp(1.0f + __expf(-x));
}

// ---------------- Kernel 1: per-(b,k) stats — LDS-staged, read-once ----------------
// 512 thr = 8 waves. Block stages 4096 px (int4+float4 = 32 KiB) into LDS once
// (coalesced, each global byte read exactly once), then wave w scans LDS for
// k = w+1 with 5 register accumulators. Grid 128 x B = 512 blocks.
__global__ __launch_bounds__(512) void k1_stats(const float* __restrict__ pred,
                                                const int* __restrict__ inst,
                                                float* __restrict__ ws) {
  const int b = blockIdx.y;
  __shared__ int4   ti[1024];
  __shared__ float4 ts[1024];
  const float4* sig4 = (const float4*)(pred + (size_t)(8*b + 5) * HW);  // ch2 t=1
  const int4*   ins4 = (const int4*)(inst + (size_t)(2*b + 1) * HW);
  const int base4 = blockIdx.x * 1024;     // 1024 int4-groups per block
  #pragma unroll
  for (int i = 0; i < 2; i++) {
    const int q = threadIdx.x + i*512;
    ti[q] = ins4[base4 + q];
    ts[q] = sig4[base4 + q];
  }
  __syncthreads();
  const int wv = threadIdx.x >> 6, lane = threadIdx.x & 63;
  const int kk = wv + 1;
  float cnt=0.f, sx=0.f, sy=0.f, ss=0.f, ss2=0.f;
  #pragma unroll
  for (int j = 0; j < 16; j++) {
    const int q = lane + 64*j;
    const int4   iv = ti[q];
    const float4 sv = ts[q];
    const int p = (base4 + q) * 4;
    const float xm0 = (float)(p & (WID-1)) * (2.0f/2047.0f);
    const float ym  = (float)(p >> 10)     * (1.0f/1023.0f);
    const float m0 = (iv.x==kk)?1.f:0.f, m1=(iv.y==kk)?1.f:0.f,
                m2 = (iv.z==kk)?1.f:0.f, m3=(iv.w==kk)?1.f:0.f;
    const float msum = (m0+m1)+(m2+m3);
    cnt += msum;
    sx  += msum*xm0 + (m1 + 2.0f*m2 + 3.0f*m3)*(2.0f/2047.0f);
    sy  += msum*ym;
    ss  += m0*sv.x + m1*sv.y + m2*sv.z + m3*sv.w;
    ss2 += m0*sv.x*sv.x + m1*sv.y*sv.y + m2*sv.z*sv.z + m3*sv.w*sv.w;
  }
  #pragma unroll
  for (int o=1;o<64;o<<=1){
    cnt+=__shfl_xor(cnt,o,64);
    sx +=__shfl_xor(sx, o,64);
    sy +=__shfl_xor(sy, o,64);
    ss +=__shfl_xor(ss, o,64);
    ss2+=__shfl_xor(ss2,o,64);
  }
  if (lane == 0) {
    float* st = ws + OFF_STATS + (b*K + wv)*5;
    atomicAdd(st+0, cnt);
    atomicAdd(st+1, sx);
    atomicAdd(st+2, sy);
    atomicAdd(st+3, ss);
    atomicAdd(st+4, ss2);
  }
}

// ---------------- Kernel 2: finalize stats + var loss ----------------
__global__ void k2_fin(float* __restrict__ ws) {
  const int t = threadIdx.x;
  if (t >= B*K) return;
  const float* st = ws + OFF_STATS + t*5;
  const float cnt = st[0], sx = st[1], sy = st[2], ss = st[3], ss2 = st[4];
  const float present = (cnt > 0.0f) ? 1.0f : 0.0f;
  const float safe = fmaxf(cnt, 1.0f);
  const float cx = sx/safe, cy = sy/safe, sm = ss/safe;
  const float var = (ss2 - 2.0f*sm*ss + sm*sm*cnt)/safe;   // N_SIGMA=1
  const float sexp = expf(10.0f * sm);
  float* fin = ws + OFF_FIN + t*4;
  fin[0]=cx; fin[1]=cy; fin[2]=-sexp; fin[3]=cnt;
  atomicAdd(ws + OFF_LOSS, present * 10.0f * var * (1.0f/3.0f));  // W_VAR=10, /(B-1)
}

// ---------------- Kernel 3: main pass — LDS histograms, register params ----------------
// template<G> so trip counts are compile-time (loads pipeline). Per-k params in
// 8 float4 REGISTERS (no per-pixel finL ds_read). k=j uniform across wave; data
// buckets are spread so same-address atomic degree stays low. Flush = plain stores.
template<int G>
__global__ __launch_bounds__(256) void k3_main(const float* __restrict__ pred,
                                               const int* __restrict__ inst,
                                               float* __restrict__ ws,
                                               unsigned int* __restrict__ part) {
  const int b = blockIdx.y, g = blockIdx.x;
  __shared__ unsigned int hist[K*NB];           // pos<<16 | cnt, 32 KiB
  for (int i = threadIdx.x; i < K*NB; i += 256) hist[i] = 0;
  float4 fr[K];
  #pragma unroll
  for (int k=0;k<K;k++){
    const float* fin = ws + OFF_FIN + (b*K + k)*4;
    fr[k] = make_float4(fin[0], fin[1], fin[2], fin[3]);  // {cx,cy,-sexp,cnt}
  }
  __syncthreads();
  const float4* p0 = (const float4*)(pred + (size_t)(8*b+1)*HW);
  const float4* p1 = (const float4*)(pred + (size_t)(8*b+3)*HW);
  const float4* p3 = (const float4*)(pred + (size_t)(8*b+7)*HW);
  const int4*   in4 = (const int4*)(inst + (size_t)(2*b+1)*HW);
  float sAcc = 0.0f;
  constexpr int CH4 = HW / (G*4);               // int4-groups per block
  const int base4 = g * CH4;
  #pragma unroll
  for (int q0 = 0; q0 < CH4; q0 += 256) {
    const int idx = base4 + q0 + threadIdx.x;
    const int4   iv = in4[idx];
    const float4 f0 = p0[idx];
    const float4 f1 = p1[idx];
    const float4 f3 = p3[idx];
    const int p = idx * 4;
    const float xm0 = (float)(p & (WID-1)) * (2.0f/2047.0f);
    const float ym  = (float)(p >> 10)     * (1.0f/1023.0f);
    const int   ivv[4] = {iv.x, iv.y, iv.z, iv.w};
    const float a0v[4] = {f0.x, f0.y, f0.z, f0.w};
    const float a1v[4] = {f1.x, f1.y, f1.z, f1.w};
    const float a3v[4] = {f3.x, f3.y, f3.z, f3.w};
    #pragma unroll
    for (int e4 = 0; e4 < 4; e4++) {
      const int ivp = ivv[e4];
      const float sex = ftanh(a0v[e4]) + xm0 + (float)e4*(2.0f/2047.0f);
      const float sey = ftanh(a1v[e4]) + ym;
      const float sd  = fsigmoid(a3v[e4]);
      if (ivp == 0) sAcc += sd*sd;
      #pragma unroll
      for (int j=0;j<K;j++){
        const float dx = sex - fr[j].x;
        const float dy = sey - fr[j].y;
        const float dist = __expf(fr[j].z*(dx*dx + dy*dy));  // (0,1]
        const bool own = (ivp == j+1);
        float e;
        if (own) { const float d = sd - dist; sAcc += d*d; e = 2.0f - 2.0f*dist; }
        else     { e = 2.0f*dist; }
        int bu = (int)(e * (NB*0.5f));
        if (bu > NB-1) bu = NB-1;
        atomicAdd(&hist[j*NB + bu], own ? 0x10001u : 1u);
      }
    }
  }
  __syncthreads();
  // plain coalesced flush (px/block <= 16384 < 65536: 16-bit fields safe)
  unsigned int* dst = part + ((size_t)b*G + g)*(K*NB);
  for (int i = threadIdx.x; i < K*NB; i += 256) dst[i] = hist[i];
  #pragma unroll
  for (int o=1;o<64;o<<=1) sAcc += __shfl_xor(sAcc, o, 64);
  __shared__ float wsum[4];
  if ((threadIdx.x & 63) == 0) wsum[threadIdx.x>>6] = sAcc;
  __syncthreads();
  if (threadIdx.x == 0) {
    const float tot = wsum[0]+wsum[1]+wsum[2]+wsum[3];
    atomicAdd(ws + OFF_LOSS, tot * (1.0f/((float)HW * 3.0f)));  // W_SEED /npix /(B-1)
  }
}

// ---------------- Kernel 4a: parallel G-way partial reduction ----------------
// grid (B*K, 8), 128 thr: block (bk,c) reduces buckets [c*128, c*128+128) over g.
__global__ __launch_bounds__(128) void k4a_reduce(const unsigned int* __restrict__ part,
                                                  unsigned int* __restrict__ red, int G) {
  const int bk = blockIdx.x, c = blockIdx.y;
  const int b = bk >> 3, k = bk & 7;
  const int bu = c*128 + threadIdx.x;
  const unsigned int* base = part + (size_t)b*G*K*NB + (size_t)k*NB + bu;
  unsigned int rc = 0, rp = 0;
  for (int g = 0; g < G; g++) {
    const unsigned int v = base[(size_t)g*K*NB];
    rc += v & 0xFFFFu;
    rp += v >> 16;
  }
  red[bk*NB + bu]            = rc;
  red[B*K*NB + bk*NB + bu]   = rp;
}

// ---------------- Kernel 4b: Lovász from reduced histogram (block scan) ----------------
__global__ __launch_bounds__(256) void k4b_lovasz(const unsigned int* __restrict__ red,
                                                   float* __restrict__ ws) {
  const int bk = blockIdx.x;                    // b*K + k
  const float cntF = ws[OFF_FIN + bk*4 + 3];
  if (cntF <= 0.0f) return;
  const double Pd = (double)cntF;
  const int t = threadIdx.x;
  const int lane = t & 63, wv = t >> 6;
  unsigned int cnt[4], pos[4];
  #pragma unroll
  for (int j = 0; j < 4; j++) {
    const int bu = NB-1 - (t*4 + j);            // descending error order
    cnt[j] = red[bk*NB + bu];
    pos[j] = red[B*K*NB + bk*NB + bu];
  }
  const int lc = (int)(cnt[0]+cnt[1]+cnt[2]+cnt[3]);
  const int lp = (int)(pos[0]+pos[1]+pos[2]+pos[3]);
  int ic = lc, ip = lp;
  #pragma unroll
  for (int o=1;o<64;o<<=1){
    const int vc = __shfl_up(ic, o, 64);
    const int vp = __shfl_up(ip, o, 64);
    if (lane >= o) { ic += vc; ip += vp; }
  }
  __shared__ int wtc[4], wtp[4];
  if (lane == 63) { wtc[wv] = ic; wtp[wv] = ip; }
  __syncthreads();
  int offc = 0, offp = 0;
  for (int w = 0; w < wv; w++) { offc += wtc[w]; offp += wtp[w]; }
  int irun = offc + ic - lc;                    // exclusive prefixes
  int crun = offp + ip - lp;
  double acc = 0.0;
  #pragma unroll
  for (int j = 0; j < 4; j++) {
    const int n = (int)cnt[j];
    if (n) {
      const int bu = NB-1 - (t*4 + j);
      const double jac0 = (irun==0) ? 0.0 : 1.0 - (Pd - crun)/(Pd + irun - crun);
      irun += n; crun += (int)pos[j];
      const double jac1 = 1.0 - (Pd - crun)/(Pd + irun - crun);
      acc += ((bu + 0.5) * (2.0/NB)) * (jac1 - jac0);
    }
  }
  #pragma unroll
  for (int o=1;o<64;o<<=1) acc += __shfl_xor(acc, o, 64);
  __shared__ double racc[4];
  if (lane == 0) racc[wv] = acc;
  __syncthreads();
  if (t == 0) {
    const double tot = racc[0]+racc[1]+racc[2]+racc[3];
    atomicAdd(ws + OFF_LOSS, (float)(tot * (1.0/3.0)));   // W_INST=1, /(B-1)
  }
}

// ---------------- Kernel 5: write output ----------------
__global__ void k5_out(const float* __restrict__ ws, float* __restrict__ out) {
  if (threadIdx.x == 0) out[0] = ws[OFF_LOSS];
}

extern "C" void kernel_launch(void* const* d_in, const int* in_sizes, int n_in,
                              void* d_out, int out_size, void* d_ws, size_t ws_size,
                              hipStream_t stream) {
  const float* pred = (const float*)d_in[0];
  const int*   inst = (const int*)d_in[1];
  float* ws  = (float*)d_ws;
  float* out = (float*)d_out;
  unsigned int* red  = ((unsigned int*)d_ws) + OFF_RED;
  unsigned int* part = ((unsigned int*)d_ws) + OFF_PART;
  // G tier by ws capacity (all divide HW/4; px/block <= 16384)
  int G = 256;
  while (G > 32 && ws_size < ((size_t)OFF_PART + (size_t)B*G*K*NB)*4) G >>= 1;
  hipMemsetAsync(d_ws, 0, (size_t)OFF_RED*4, stream);   // zero LOSS/STATS/FIN only
  k1_stats<<<dim3(128,B), 512, 0, stream>>>(pred, inst, ws);
  k2_fin  <<<1, 64, 0, stream>>>(ws);
  if      (G == 256) k3_main<256><<<dim3(256,B), 256, 0, stream>>>(pred, inst, ws, part);
  else if (G == 128) k3_main<128><<<dim3(128,B), 256, 0, stream>>>(pred, inst, ws, part);
  else if (G ==  64) k3_main< 64><<<dim3( 64,B), 256, 0, stream>>>(pred, inst, ws, part);
  else               k3_main< 32><<<dim3( 32,B), 256, 0, stream>>>(pred, inst, ws, part);
  k4a_reduce<<<dim3(B*K, 8), 128, 0, stream>>>(part, red, G);
  k4b_lovasz<<<B*K, 256, 0, stream>>>(red, ws);
  k5_out  <<<1, 64, 0, stream>>>(ws, out);
}

// Round 6
// 141.837 us; speedup vs baseline: 2.0102x; 1.5850x over previous
//
#include <hip/hip_runtime.h>

#define H 512
#define WID 1024
#define HW (H*WID)
#define B 4
#define K 8
#define NB 1024
#define NBLK1 128                          // k1 blocks per image

// ws word (4-byte) layout
#define OFF_LOSS  0
#define OFF_FIN   16                       // B*K*8 floats: a,bx,by,d0,cnt,pad*3
#define OFF_SPART 512                      // B*K*NBLK1*5 floats (k1 partials)
#define OFF_RED   (OFF_SPART + B*K*NBLK1*5)    // 2*B*K*NB u32
#define OFF_PART  (OFF_RED + 2*B*K*NB)     // B*G*K*NB packed u32 (pos<<16|cnt)

static __device__ __forceinline__ float frcp(float x){
#if __has_builtin(__builtin_amdgcn_rcpf)
  return __builtin_amdgcn_rcpf(x);
#else
  return 1.0f / x;
#endif
}
static __device__ __forceinline__ float fexp2(float x){
#if __has_builtin(__builtin_amdgcn_exp2f)
  return __builtin_amdgcn_exp2f(x);
#else
  return exp2f(x);
#endif
}
static __device__ __forceinline__ float ftanh(float x){
  return 1.0f - 2.0f * frcp(__expf(2.0f*x) + 1.0f);
}
static __device__ __forceinline__ float fsigmoid(float x){
  return frcp(1.0f + __expf(-x));
}

// ---------------- Kernel 1: per-(b,k) stats — LDS staged, NO global atomics ----------------
// 512 thr = 8 waves; wave w owns k=w+1. Finale: block-level LDS reduce, then 40
// plain coalesced stores to spart slab (fire-and-forget; no L2 atomic ping-pong).
__global__ __launch_bounds__(512) void k1_stats(const float* __restrict__ pred,
                                                const int* __restrict__ inst,
                                                float* __restrict__ ws) {
  const int b = blockIdx.y;
  __shared__ int4   ti[1024];
  __shared__ float4 ts[1024];
  __shared__ float  part5[K][5];
  const float4* sig4 = (const float4*)(pred + (size_t)(8*b + 5) * HW);  // ch2 t=1
  const int4*   ins4 = (const int4*)(inst + (size_t)(2*b + 1) * HW);
  const int base4 = blockIdx.x * 1024;     // 1024 int4-groups per block
  #pragma unroll
  for (int i = 0; i < 2; i++) {
    const int q = threadIdx.x + i*512;
    ti[q] = ins4[base4 + q];
    ts[q] = sig4[base4 + q];
  }
  __syncthreads();
  const int wv = threadIdx.x >> 6, lane = threadIdx.x & 63;
  const int kk = wv + 1;
  float cnt=0.f, sx=0.f, sy=0.f, ss=0.f, ss2=0.f;
  #pragma unroll
  for (int j = 0; j < 16; j++) {
    const int q = lane + 64*j;
    const int4   iv = ti[q];
    const float4 sv = ts[q];
    const int p = (base4 + q) * 4;
    const float xm0 = (float)(p & (WID-1)) * (2.0f/2047.0f);
    const float ym  = (float)(p >> 10)     * (1.0f/1023.0f);
    const float m0 = (iv.x==kk)?1.f:0.f, m1=(iv.y==kk)?1.f:0.f,
                m2 = (iv.z==kk)?1.f:0.f, m3=(iv.w==kk)?1.f:0.f;
    const float msum = (m0+m1)+(m2+m3);
    cnt += msum;
    sx  += msum*xm0 + (m1 + 2.0f*m2 + 3.0f*m3)*(2.0f/2047.0f);
    sy  += msum*ym;
    ss  += m0*sv.x + m1*sv.y + m2*sv.z + m3*sv.w;
    ss2 += m0*sv.x*sv.x + m1*sv.y*sv.y + m2*sv.z*sv.z + m3*sv.w*sv.w;
  }
  #pragma unroll
  for (int o=1;o<64;o<<=1){
    cnt+=__shfl_xor(cnt,o,64);
    sx +=__shfl_xor(sx, o,64);
    sy +=__shfl_xor(sy, o,64);
    ss +=__shfl_xor(ss, o,64);
    ss2+=__shfl_xor(ss2,o,64);
  }
  if (lane == 0) {
    part5[wv][0]=cnt; part5[wv][1]=sx; part5[wv][2]=sy; part5[wv][3]=ss; part5[wv][4]=ss2;
  }
  __syncthreads();
  if (threadIdx.x < K*5) {
    const int w = threadIdx.x / 5, c = threadIdx.x % 5;
    ws[OFF_SPART + ((size_t)(b*K + w)*NBLK1 + blockIdx.x)*5 + c] = part5[w][c];
  }
}

// ---------------- Kernel 2: reduce spart, finalize params, var loss ----------------
// 1 block, 256 thr: thread t -> bk = t>>3, slice s = t&7 (16 blocks each).
__global__ __launch_bounds__(256) void k2_fin(float* __restrict__ ws) {
  const int t = threadIdx.x;
  const int bk = t >> 3, s = t & 7;
  float a0=0.f,a1=0.f,a2=0.f,a3=0.f,a4=0.f;
  for (int j = 0; j < NBLK1/8; j++) {
    const float* p = ws + OFF_SPART + ((size_t)bk*NBLK1 + (s + 8*j))*5;
    a0+=p[0]; a1+=p[1]; a2+=p[2]; a3+=p[3]; a4+=p[4];
  }
  #pragma unroll
  for (int o=1;o<8;o<<=1){
    a0+=__shfl_xor(a0,o,64); a1+=__shfl_xor(a1,o,64); a2+=__shfl_xor(a2,o,64);
    a3+=__shfl_xor(a3,o,64); a4+=__shfl_xor(a4,o,64);
  }
  __shared__ float vloc[32];
  if (s == 0) {
    const float cnt=a0, sx=a1, sy=a2, ss=a3, ss2=a4;
    const float present = (cnt > 0.0f) ? 1.0f : 0.0f;
    const float safe = fmaxf(cnt, 1.0f);
    const float cx = sx/safe, cy = sy/safe, sm = ss/safe;
    const float var = (ss2 - 2.0f*sm*ss + sm*sm*cnt)/safe;   // N_SIGMA=1
    const float sexp = expf(10.0f * sm);
    const float L2E = 1.4426950408889634f;
    float* fin = ws + OFF_FIN + bk*8;
    fin[0] = -sexp*L2E;                       // a   (coeff of px^2+py^2)
    fin[1] =  2.0f*sexp*cx*L2E;               // bx
    fin[2] =  2.0f*sexp*cy*L2E;               // by
    fin[3] = -sexp*(cx*cx + cy*cy)*L2E + 10.0f;  // d0 (+10 folds the x1024 bucket scale)
    fin[4] = cnt;
    vloc[bk] = present * 10.0f * var * (1.0f/3.0f);   // W_VAR=10, /(B-1)
  }
  __syncthreads();
  if (t == 0) {
    float v = 0.f;
    #pragma unroll
    for (int i = 0; i < 32; i++) v += vloc[i];
    atomicAdd(ws + OFF_LOSS, v);
  }
}

// ---------------- Kernel 3: main pass — 3-FMA log2-domain bucketing ----------------
// bucket_notown = (int)2^u, u = a*t2 + bx*px + by*py + d0 (scale folded); own =
// 1023 - vi. dist for seed loss = v/1024. Flush = plain stores to part slab.
template<int G>
__global__ __launch_bounds__(256) void k3_main(const float* __restrict__ pred,
                                               const int* __restrict__ inst,
                                               float* __restrict__ ws,
                                               unsigned int* __restrict__ part) {
  const int b = blockIdx.y, g = blockIdx.x;
  __shared__ unsigned int hist[K*NB];           // pos<<16 | cnt, 32 KiB
  for (int i = threadIdx.x; i < K*NB; i += 256) hist[i] = 0;
  float4 fr[K];
  #pragma unroll
  for (int k=0;k<K;k++){
    const float* fin = ws + OFF_FIN + (b*K + k)*8;
    fr[k] = make_float4(fin[0], fin[1], fin[2], fin[3]);  // {a,bx,by,d0}
  }
  __syncthreads();
  const float4* p0 = (const float4*)(pred + (size_t)(8*b+1)*HW);
  const float4* p1 = (const float4*)(pred + (size_t)(8*b+3)*HW);
  const float4* p3 = (const float4*)(pred + (size_t)(8*b+7)*HW);
  const int4*   in4 = (const int4*)(inst + (size_t)(2*b+1)*HW);
  float sAcc = 0.0f;
  constexpr int CH4 = HW / (G*4);
  const int base4 = g * CH4;
  #pragma unroll
  for (int q0 = 0; q0 < CH4; q0 += 256) {
    const int idx = base4 + q0 + threadIdx.x;
    const int4   iv = in4[idx];
    const float4 f0 = p0[idx];
    const float4 f1 = p1[idx];
    const float4 f3 = p3[idx];
    const int p = idx * 4;
    const float xm0 = (float)(p & (WID-1)) * (2.0f/2047.0f);
    const float ym  = (float)(p >> 10)     * (1.0f/1023.0f);
    const int   ivv[4] = {iv.x, iv.y, iv.z, iv.w};
    const float a0v[4] = {f0.x, f0.y, f0.z, f0.w};
    const float a1v[4] = {f1.x, f1.y, f1.z, f1.w};
    const float a3v[4] = {f3.x, f3.y, f3.z, f3.w};
    #pragma unroll
    for (int e4 = 0; e4 < 4; e4++) {
      const int ivp = ivv[e4];
      const float px = ftanh(a0v[e4]) + xm0 + (float)e4*(2.0f/2047.0f);
      const float py = ftanh(a1v[e4]) + ym;
      const float sd = fsigmoid(a3v[e4]);
      const float t2 = px*px + py*py;
      float down = 0.0f;
      #pragma unroll
      for (int j=0;j<K;j++){
        const float u = fmaf(fr[j].x, t2, fmaf(fr[j].y, px, fmaf(fr[j].z, py, fr[j].w)));
        const float v = fexp2(u);                 // 1024*dist in [0,1024]
        int vi = (int)v; vi = (vi > NB-1) ? NB-1 : vi;
        const bool own = (ivp == j+1);
        const int bu = own ? (NB-1 - vi) : vi;
        if (own) down = v;
        atomicAdd(&hist[j*NB + bu], own ? 0x10001u : 1u);
      }
      const float d  = (ivp == 0) ? 0.0f : down * (1.0f/1024.0f);
      const float df = sd - d;
      sAcc += df*df;                              // bg: sd^2; fg: (sd-dist)^2
    }
  }
  __syncthreads();
  unsigned int* dst = part + ((size_t)b*G + g)*(K*NB);
  for (int i = threadIdx.x; i < K*NB; i += 256) dst[i] = hist[i];
  #pragma unroll
  for (int o=1;o<64;o<<=1) sAcc += __shfl_xor(sAcc, o, 64);
  __shared__ float wsum[4];
  if ((threadIdx.x & 63) == 0) wsum[threadIdx.x>>6] = sAcc;
  __syncthreads();
  if (threadIdx.x == 0) {
    const float tot = wsum[0]+wsum[1]+wsum[2]+wsum[3];
    atomicAdd(ws + OFF_LOSS, tot * (1.0f/((float)HW * 3.0f)));  // W_SEED /npix /(B-1)
  }
}

// ---------------- Kernel 4a: parallel G-way partial reduction ----------------
__global__ __launch_bounds__(128) void k4a_reduce(const unsigned int* __restrict__ part,
                                                  unsigned int* __restrict__ red, int G) {
  const int bk = blockIdx.x, c = blockIdx.y;
  const int b = bk >> 3, k = bk & 7;
  const int bu = c*128 + threadIdx.x;
  const unsigned int* base = part + (size_t)b*G*K*NB + (size_t)k*NB + bu;
  unsigned int rc = 0, rp = 0;
  #pragma unroll 4
  for (int g = 0; g < G; g++) {
    const unsigned int v = base[(size_t)g*K*NB];
    rc += v & 0xFFFFu;
    rp += v >> 16;
  }
  red[bk*NB + bu]            = rc;
  red[B*K*NB + bk*NB + bu]   = rp;
}

// ---------------- Kernel 4b: Lovász from reduced histogram (block scan) ----------------
__global__ __launch_bounds__(256) void k4b_lovasz(const unsigned int* __restrict__ red,
                                                   float* __restrict__ ws) {
  const int bk = blockIdx.x;                    // b*K + k
  const float cntF = ws[OFF_FIN + bk*8 + 4];
  if (cntF <= 0.0f) return;
  const double Pd = (double)cntF;
  const int t = threadIdx.x;
  const int lane = t & 63, wv = t >> 6;
  unsigned int cnt[4], pos[4];
  #pragma unroll
  for (int j = 0; j < 4; j++) {
    const int bu = NB-1 - (t*4 + j);            // descending error order
    cnt[j] = red[bk*NB + bu];
    pos[j] = red[B*K*NB + bk*NB + bu];
  }
  const int lc = (int)(cnt[0]+cnt[1]+cnt[2]+cnt[3]);
  const int lp = (int)(pos[0]+pos[1]+pos[2]+pos[3]);
  int ic = lc, ip = lp;
  #pragma unroll
  for (int o=1;o<64;o<<=1){
    const int vc = __shfl_up(ic, o, 64);
    const int vp = __shfl_up(ip, o, 64);
    if (lane >= o) { ic += vc; ip += vp; }
  }
  __shared__ int wtc[4], wtp[4];
  if (lane == 63) { wtc[wv] = ic; wtp[wv] = ip; }
  __syncthreads();
  int offc = 0, offp = 0;
  for (int w = 0; w < wv; w++) { offc += wtc[w]; offp += wtp[w]; }
  int irun = offc + ic - lc;                    // exclusive prefixes
  int crun = offp + ip - lp;
  double acc = 0.0;
  #pragma unroll
  for (int j = 0; j < 4; j++) {
    const int n = (int)cnt[j];
    if (n) {
      const int bu = NB-1 - (t*4 + j);
      const double jac0 = (irun==0) ? 0.0 : 1.0 - (Pd - crun)/(Pd + irun - crun);
      irun += n; crun += (int)pos[j];
      const double jac1 = 1.0 - (Pd - crun)/(Pd + irun - crun);
      acc += ((bu + 0.5) * (2.0/NB)) * (jac1 - jac0);
    }
  }
  #pragma unroll
  for (int o=1;o<64;o<<=1) acc += __shfl_xor(acc, o, 64);
  __shared__ double racc[4];
  if (lane == 0) racc[wv] = acc;
  __syncthreads();
  if (t == 0) {
    const double tot = racc[0]+racc[1]+racc[2]+racc[3];
    atomicAdd(ws + OFF_LOSS, (float)(tot * (1.0/3.0)));   // W_INST=1, /(B-1)
  }
}

// ---------------- Kernel 5: write output ----------------
__global__ void k5_out(const float* __restrict__ ws, float* __restrict__ out) {
  if (threadIdx.x == 0) out[0] = ws[OFF_LOSS];
}

extern "C" void kernel_launch(void* const* d_in, const int* in_sizes, int n_in,
                              void* d_out, int out_size, void* d_ws, size_t ws_size,
                              hipStream_t stream) {
  const float* pred = (const float*)d_in[0];
  const int*   inst = (const int*)d_in[1];
  float* ws  = (float*)d_ws;
  float* out = (float*)d_out;
  unsigned int* red  = ((unsigned int*)d_ws) + OFF_RED;
  unsigned int* part = ((unsigned int*)d_ws) + OFF_PART;
  int G = 128;
  while (G > 32 && ws_size < ((size_t)OFF_PART + (size_t)B*G*K*NB)*4) G >>= 1;
  hipMemsetAsync(d_ws, 0, (size_t)OFF_FIN*4 + 64, stream);   // zero LOSS region
  k1_stats<<<dim3(NBLK1,B), 512, 0, stream>>>(pred, inst, ws);
  k2_fin  <<<1, 256, 0, stream>>>(ws);
  if      (G == 128) k3_main<128><<<dim3(128,B), 256, 0, stream>>>(pred, inst, ws, part);
  else if (G ==  64) k3_main< 64><<<dim3( 64,B), 256, 0, stream>>>(pred, inst, ws, part);
  else               k3_main< 32><<<dim3( 32,B), 256, 0, stream>>>(pred, inst, ws, part);
  k4a_reduce<<<dim3(B*K, 8), 128, 0, stream>>>(part, red, G);
  k4b_lovasz<<<B*K, 256, 0, stream>>>(red, ws);
  k5_out  <<<1, 64, 0, stream>>>(ws, out);
}